// Round 5
// baseline (235.687 us; speedup 1.0000x reference)
//
#include <hip/hip_runtime.h>
#include <stdint.h>

typedef unsigned short ushort_t;
typedef __attribute__((ext_vector_type(8))) short short8;
typedef __attribute__((ext_vector_type(4))) float floatx4;
typedef __attribute__((ext_vector_type(4))) unsigned short ushortx4;
typedef __attribute__((ext_vector_type(8))) unsigned short ushortx8;

#define B_   16
#define CIN  128
#define CH   256
#define HW   96
#define HP   98

// ws layout (bytes)
#define XPAD_ELEMS (B_*HP*HP*CIN)            // bf16 elems
#define HPAD_ELEMS (B_*HP*HP*CH)             // bf16 elems
#define XPAD_OFF 0
#define HPAD_OFF (XPAD_ELEMS*2)
#define W1T_OFF  (HPAD_OFF + HPAD_ELEMS*2)
#define W2T_OFF  (W1T_OFF + 256*1152*2)

__device__ __forceinline__ ushort_t f2bf(float f){
  uint32_t u = __float_as_uint(f);
  u += 0x7FFF + ((u >> 16) & 1);   // RNE
  return (ushort_t)(u >> 16);
}
__device__ __forceinline__ float bf2f(ushort_t h){
  return __uint_as_float(((uint32_t)h) << 16);
}
__device__ __forceinline__ void async_ld16(void* lds, const void* g){
  __builtin_amdgcn_global_load_lds(
      (const __attribute__((address_space(1))) void*)g,
      (__attribute__((address_space(3))) void*)lds, 16, 0, 0);
}

// Zero the 1-px border cells of a padded NHWC tensor. C2 = channels/2 (uint32 words per cell).
__global__ void zero_border(uint32_t* __restrict__ base, int C2){
  int tid = blockIdx.x*256 + threadIdx.x;
  int perimg = 388*C2;
  int total = B_*perimg;
  if (tid >= total) return;
  int b = tid / perimg; int r = tid % perimg;
  int cell = r / C2;    int cu = r % C2;
  int y, x;
  if      (cell < 98)  { y = 0;            x = cell;       }
  else if (cell < 196) { y = 97;           x = cell - 98;  }
  else if (cell < 292) { y = cell - 195;   x = 0;          }
  else                 { y = cell - 291;   x = 97;         }
  base[((b*HP + y)*HP + x)*C2 + cu] = 0u;
}

// NCHW fp32 -> padded NHWC bf16 via LDS transpose. One block = (b, 4 y-rows, 32x, 32c).
__global__ void transform_x(const float* __restrict__ x, ushort_t* __restrict__ xpad){
  __shared__ float lds[32][33];
  int bid = blockIdx.x;              // 4608 = 16 b * 24 yt * 3 xt * 4 ct
  int ct = bid & 3; int xt = (bid>>2) % 3; int yt = (bid/12) % 24; int b = bid/288;
  int c0 = ct*32, x0 = xt*32, y0 = yt*4;
  int t = threadIdx.x;
  for (int yy=0; yy<4; ++yy){
    int y = y0 + yy;
    #pragma unroll
    for (int rep=0; rep<4; ++rep){
      int idx = rep*256 + t;
      int ci = idx >> 5, xj = idx & 31;
      lds[ci][xj] = x[((b*CIN + c0+ci)*HW + y)*HW + x0 + xj];
    }
    __syncthreads();
    int px = t >> 3, quad = t & 7;
    ushortx4 v;
    #pragma unroll
    for (int k=0;k<4;k++) v[k] = f2bf(lds[quad*4+k][px]);
    *(ushortx4*)&xpad[(((b*HP + y+1)*HP) + x0+px+1)*CIN + c0 + quad*4] = v;
    __syncthreads();
  }
}

// w1 [256][128][3][3] fp32 -> w1t [256][1152] bf16, k = tap*128 + c
__global__ void transform_w1(const float* __restrict__ w1, ushort_t* __restrict__ w1t){
  int tid = blockIdx.x*256 + threadIdx.x;   // 294912 exact
  int o = tid / 1152, k = tid - o*1152;
  int tap = k >> 7, c = k & 127;
  w1t[tid] = f2bf(w1[(o*CIN + c)*9 + tap]);
}

// w2 [2][256][3][3] fp32 -> w2t [9][256][2] fp32
__global__ void transform_w2(const float* __restrict__ w2, float* __restrict__ w2t){
  int tid = blockIdx.x*256 + threadIdx.x;
  if (tid >= 4608) return;
  int ch = tid & 1, c = (tid >> 1) & 255, tap = tid >> 9;
  w2t[tid] = w2[(ch*CH + c)*9 + tap];
}

// ---------------------------------------------------------------------------
// conv1 v2: implicit GEMM, M=256 x N=147456 x K=1152, BK=32 (36 K-tiles),
// 256x256 tile, 512 thr / 8 waves (2M x 4N), quad-buffered LDS (depth-2
// pipeline), counted vmcnt(4) (never drains in main loop), raw s_barrier,
// T2 XOR-swizzle (stored octet = logical ^ (row&3), pre-swizzled gload src),
// T5 setprio around MFMA clusters.
// Pipeline ledger: iter kt stages K_{kt+2} (4 loads/thread, 2 per phase);
// at iter-kt entry outstanding = K_{kt+1}(4 youngest) + K_kt stragglers ->
// vmcnt(4) guarantees K_kt landed; s_barrier makes it block-wide. Buffer
// (kt+2)&3 was last read in iter kt-2 (two barriers ago) -> no WAR race.
// Tail: iter 34 stages nothing; iter 35 peeled with vmcnt(0).
// ---------------------------------------------------------------------------
#define C1_BODY(KT, VMN) { \
  asm volatile("s_waitcnt vmcnt(" #VMN ")" ::: "memory"); \
  __builtin_amdgcn_s_barrier(); \
  __builtin_amdgcn_sched_barrier(0); \
  const int kt_ = (KT); \
  const int buf_ = kt_ & 3; \
  const ushort_t* Ab = &Alds[buf_*8192]; \
  const ushort_t* Bb = &Blds[buf_*8192]; \
  const int kt2_ = kt_ + 2; \
  if (kt2_ < 36) { \
    const int buf2_ = kt2_ & 3; \
    const int tap2_ = kt2_ >> 2; \
    const int dy2_ = (tap2_*86) >> 8; const int dx2_ = tap2_ - dy2_*3; \
    const int bd2_ = (dy2_*HP + dx2_)*CIN + (kt2_ & 3)*32; \
    async_ld16(&Alds[buf2_*8192 + adst0], &w1t[asrc0 + kt2_*32]); \
    async_ld16(&Blds[buf2_*8192 + adst0], &xpad[bsrc0 + bd2_]); \
  } \
  short8 af[4], bfr[4]; \
  _Pragma("unroll") \
  for (int mf=0; mf<4; ++mf) af[mf] = *(const short8*)&Ab[aoffbase + mf*512]; \
  _Pragma("unroll") \
  for (int nf=0; nf<4; ++nf) bfr[nf] = *(const short8*)&Bb[boffbase + nf*512]; \
  __builtin_amdgcn_s_setprio(1); \
  _Pragma("unroll") \
  for (int mf=0; mf<4; ++mf) \
    _Pragma("unroll") \
    for (int nf=0; nf<4; ++nf) \
      acc[mf][nf] = __builtin_amdgcn_mfma_f32_16x16x32_bf16(af[mf], bfr[nf], acc[mf][nf], 0,0,0); \
  __builtin_amdgcn_s_setprio(0); \
  __builtin_amdgcn_s_barrier(); \
  __builtin_amdgcn_sched_barrier(0); \
  if (kt2_ < 36) { \
    const int buf2_ = kt2_ & 3; \
    const int tap2_ = kt2_ >> 2; \
    const int dy2_ = (tap2_*86) >> 8; const int dx2_ = tap2_ - dy2_*3; \
    const int bd2_ = (dy2_*HP + dx2_)*CIN + (kt2_ & 3)*32; \
    async_ld16(&Alds[buf2_*8192 + adst1], &w1t[asrc1 + kt2_*32]); \
    async_ld16(&Blds[buf2_*8192 + adst1], &xpad[bsrc1 + bd2_]); \
  } \
  short8 af4[4]; \
  _Pragma("unroll") \
  for (int mf=0; mf<4; ++mf) af4[mf] = *(const short8*)&Ab[aoffbase + (mf+4)*512]; \
  __builtin_amdgcn_s_setprio(1); \
  _Pragma("unroll") \
  for (int mf=0; mf<4; ++mf) \
    _Pragma("unroll") \
    for (int nf=0; nf<4; ++nf) \
      acc[mf+4][nf] = __builtin_amdgcn_mfma_f32_16x16x32_bf16(af4[mf], bfr[nf], acc[mf+4][nf], 0,0,0); \
  __builtin_amdgcn_s_setprio(0); \
}

__global__ __launch_bounds__(512, 2) void conv1(const ushort_t* __restrict__ xpad,
                                                const ushort_t* __restrict__ w1t,
                                                const float* __restrict__ b1,
                                                ushort_t* __restrict__ hpad){
  __shared__ __align__(16) ushort_t Alds[4*8192];   // 4 bufs x 256 rows x 32 (64 KB)
  __shared__ __align__(16) ushort_t Blds[4*8192];   // 64 KB
  int orig = blockIdx.x;
  int bid = (orig & 7) * 72 + (orig >> 3);          // XCD swizzle, 576 % 8 == 0
  int b = bid / 36; int rem = bid - b*36;
  int y0 = (rem/3)*8, x0 = (rem - (rem/3)*3)*32;    // 8y x 32x pixel tile
  int t = threadIdx.x;
  int lane = t & 63, wave = t >> 6;
  int wm = wave & 1, wn = wave >> 1;                // 2M x 4N waves
  int r = lane & 15, q = lane >> 4;

  // staging maps: granule u = pass*512 + t; row = u>>2, logical oct = u&3;
  // stored linearly at u*8 ushorts; global source uses oct ^ (row&3).
  int u0 = t, u1 = 512 + t;
  int row0 = u0 >> 2, soct0 = (u0 & 3) ^ (row0 & 3);
  int row1 = u1 >> 2, soct1 = (u1 & 3) ^ (row1 & 3);
  const int adst0 = u0*8, adst1 = u1*8;
  const int asrc0 = row0*1152 + soct0*8;
  const int asrc1 = row1*1152 + soct1*8;
  const int bsrc0 = ((b*HP + y0 + (row0>>5))*HP + x0 + (row0&31))*CIN + soct0*8;
  const int bsrc1 = ((b*HP + y0 + (row1>>5))*HP + x0 + (row1&31))*CIN + soct1*8;

  // fragment read offsets (ushort units): row&3 == r&3 for all frag rows
  const int koffA = (q ^ (r & 3)) * 8;
  const int aoffbase = (wm*128 + r)*32 + koffA;     // + mf*512
  const int boffbase = (wn*64  + r)*32 + koffA;     // + nf*512

  floatx4 acc[8][4];
  #pragma unroll
  for (int i=0;i<8;i++)
    #pragma unroll
    for (int j=0;j<4;j++) acc[i][j] = (floatx4){0.f,0.f,0.f,0.f};

  // prologue: stage K0 -> buf0, K1 -> buf1 (bd(0)=0, bd(1)=32)
  async_ld16(&Alds[0*8192 + adst0], &w1t[asrc0]);
  async_ld16(&Blds[0*8192 + adst0], &xpad[bsrc0]);
  async_ld16(&Alds[0*8192 + adst1], &w1t[asrc1]);
  async_ld16(&Blds[0*8192 + adst1], &xpad[bsrc1]);
  async_ld16(&Alds[1*8192 + adst0], &w1t[asrc0 + 32]);
  async_ld16(&Blds[1*8192 + adst0], &xpad[bsrc0 + 32]);
  async_ld16(&Alds[1*8192 + adst1], &w1t[asrc1 + 32]);
  async_ld16(&Blds[1*8192 + adst1], &xpad[bsrc1 + 32]);

  for (int kt=0; kt<35; ++kt){
    C1_BODY(kt, 4)
  }
  C1_BODY(35, 0)

  // epilogue: +bias, ReLU, bf16, store padded NHWC h
  #pragma unroll
  for (int mf=0; mf<8; ++mf){
    int o = wm*128 + mf*16 + q*4;
    float bias0 = b1[o], bias1 = b1[o+1], bias2 = b1[o+2], bias3 = b1[o+3];
    #pragma unroll
    for (int nf=0; nf<4; ++nf){
      int n = wn*64 + nf*16 + r;
      int ty = n >> 5, tx = n & 31;
      ushortx4 v;
      v[0] = f2bf(fmaxf(acc[mf][nf][0] + bias0, 0.f));
      v[1] = f2bf(fmaxf(acc[mf][nf][1] + bias1, 0.f));
      v[2] = f2bf(fmaxf(acc[mf][nf][2] + bias2, 0.f));
      v[3] = f2bf(fmaxf(acc[mf][nf][3] + bias3, 0.f));
      *(ushortx4*)&hpad[((b*HP + y0+ty+1)*HP + (x0+tx+1))*CH + o] = v;
    }
  }
}

// conv2: LDS-staged direct 3x3. Block = 8x8 output tile, halo 10x10 cells x 512B
// staged into LDS (51.2 KB) via global_load_lds: LDS dest linear, global SOURCE
// pre-swizzled chunk ^ (cell&7); reads apply the same XOR (both-sides involution).
// Wave = channel quarter (w addresses wave-uniform -> scalar cache); lane = pixel.
__global__ __launch_bounds__(256) void conv2(const ushort_t* __restrict__ hpad,
                                             const float* __restrict__ w2t,
                                             const float* __restrict__ b2,
                                             float* __restrict__ out){
  __shared__ __align__(16) ushort_t hlds[25600];   // 100 cells * 256 ushorts
  __shared__ float part[4][64][2];
  int bid = blockIdx.x;              // 2304 = 16 b * 12 yt * 12 xt
  int b = bid / 144; int rem = bid - b*144;
  int yt = rem / 12, xt = rem - yt*12;
  int y0 = yt*8, x0 = xt*8;          // padded window base = (y0, x0)
  int t = threadIdx.x;
  int wave = t >> 6, lane = t & 63;

  // stage 3200 x 16B chunks, pre-swizzled source
  for (int pass=0; pass<13; ++pass){
    int u = pass*256 + t;
    if (u < 3200){
      int cell = u >> 5, cf = u & 31;
      int hy = cell / 10, hx = cell - hy*10;
      const ushort_t* src = hpad + ((b*HP + y0+hy)*HP + (x0+hx))*CH
                                 + ((cf ^ (cell & 7)) << 3);
      async_ld16(&hlds[(pass*256 + wave*64)*8], src);
    }
  }
  __syncthreads();

  int q = __builtin_amdgcn_readfirstlane(wave);    // channel quarter, provably uniform
  int ty = lane >> 3, tx = lane & 7;
  float a0 = 0.f, a1 = 0.f;
  for (int tap=0; tap<9; ++tap){
    int dy = tap/3, dxx = tap - dy*3;
    int cell = (ty+dy)*10 + (tx+dxx);
    int s = cell & 7;
    const float* wp = w2t + (tap*256 + q*64)*2;    // scalar pointer
    #pragma unroll
    for (int g=0; g<8; ++g){
      int j = q*8 + g;
      ushortx8 hv = *(const ushortx8*)&hlds[cell*256 + ((j ^ s) << 3)];
      #pragma unroll
      for (int i=0;i<8;i++){
        float hf = bf2f(hv[i]);
        a0 = fmaf(hf, wp[(g*8+i)*2    ], a0);
        a1 = fmaf(hf, wp[(g*8+i)*2 + 1], a1);
      }
    }
  }
  part[wave][lane][0] = a0;
  part[wave][lane][1] = a1;
  __syncthreads();
  if (t < 128){
    int sel = t >> 6, pix = t & 63;
    float v = part[0][pix][sel] + part[1][pix][sel]
            + part[2][pix][sel] + part[3][pix][sel] + b2[sel];
    int yy = y0 + (pix >> 3), xx = x0 + (pix & 7);
    out[(b*2 + sel)*9216 + yy*96 + xx] = v;
  }
}

extern "C" void kernel_launch(void* const* d_in, const int* in_sizes, int n_in,
                              void* d_out, int out_size, void* d_ws, size_t ws_size,
                              hipStream_t stream){
  const float* x  = (const float*)d_in[0];
  const float* w1 = (const float*)d_in[1];
  const float* b1 = (const float*)d_in[2];
  const float* w2 = (const float*)d_in[3];
  const float* b2 = (const float*)d_in[4];
  float* out = (float*)d_out;
  char* ws = (char*)d_ws;
  ushort_t* xpad = (ushort_t*)(ws + XPAD_OFF);
  ushort_t* hpad = (ushort_t*)(ws + HPAD_OFF);
  ushort_t* w1t  = (ushort_t*)(ws + W1T_OFF);
  float*    w2t  = (float*)(ws + W2T_OFF);

  hipLaunchKernelGGL(zero_border, dim3(16*388*64/256),  dim3(256), 0, stream, (uint32_t*)xpad, 64);
  hipLaunchKernelGGL(zero_border, dim3(16*388*128/256), dim3(256), 0, stream, (uint32_t*)hpad, 128);
  hipLaunchKernelGGL(transform_x,  dim3(4608),  dim3(256), 0, stream, x, xpad);
  hipLaunchKernelGGL(transform_w1, dim3(1152),  dim3(256), 0, stream, w1, w1t);
  hipLaunchKernelGGL(transform_w2, dim3(18),    dim3(256), 0, stream, w2, w2t);
  hipLaunchKernelGGL(conv1, dim3(576),  dim3(512), 0, stream, xpad, w1t, b1, hpad);
  hipLaunchKernelGGL(conv2, dim3(2304), dim3(256), 0, stream, hpad, w2t, b2, out);
}

// Round 6
// 177.296 us; speedup vs baseline: 1.3293x; 1.3293x over previous
//
#include <hip/hip_runtime.h>
#include <stdint.h>

typedef unsigned short ushort_t;
typedef __attribute__((ext_vector_type(8))) short short8;
typedef __attribute__((ext_vector_type(4))) float floatx4;
typedef __attribute__((ext_vector_type(4))) unsigned short ushortx4;
typedef __attribute__((ext_vector_type(8))) unsigned short ushortx8;

#define B_   16
#define CIN  128
#define CH   256
#define HW   96
#define HP   98

// ws layout (bytes)
#define XPAD_ELEMS (B_*HP*HP*CIN)            // bf16 elems
#define HPAD_ELEMS (B_*HP*HP*CH)             // bf16 elems
#define XPAD_OFF 0
#define HPAD_OFF (XPAD_ELEMS*2)
#define W1T_OFF  (HPAD_OFF + HPAD_ELEMS*2)
#define W2T_OFF  (W1T_OFF + 256*1152*2)

__device__ __forceinline__ ushort_t f2bf(float f){
  uint32_t u = __float_as_uint(f);
  u += 0x7FFF + ((u >> 16) & 1);   // RNE
  return (ushort_t)(u >> 16);
}
__device__ __forceinline__ float bf2f(ushort_t h){
  return __uint_as_float(((uint32_t)h) << 16);
}
__device__ __forceinline__ void async_ld16(void* lds, const void* g){
  __builtin_amdgcn_global_load_lds(
      (const __attribute__((address_space(1))) void*)g,
      (__attribute__((address_space(3))) void*)lds, 16, 0, 0);
}

// Zero the 1-px border cells of a padded NHWC tensor. C2 = channels/2 (uint32 words per cell).
__global__ void zero_border(uint32_t* __restrict__ base, int C2){
  int tid = blockIdx.x*256 + threadIdx.x;
  int perimg = 388*C2;
  int total = B_*perimg;
  if (tid >= total) return;
  int b = tid / perimg; int r = tid % perimg;
  int cell = r / C2;    int cu = r % C2;
  int y, x;
  if      (cell < 98)  { y = 0;            x = cell;       }
  else if (cell < 196) { y = 97;           x = cell - 98;  }
  else if (cell < 292) { y = cell - 195;   x = 0;          }
  else                 { y = cell - 291;   x = 97;         }
  base[((b*HP + y)*HP + x)*C2 + cu] = 0u;
}

// NCHW fp32 -> padded NHWC bf16 via LDS transpose. One block = (b, 4 y-rows, 32x, 32c).
__global__ void transform_x(const float* __restrict__ x, ushort_t* __restrict__ xpad){
  __shared__ float lds[32][33];
  int bid = blockIdx.x;              // 4608 = 16 b * 24 yt * 3 xt * 4 ct
  int ct = bid & 3; int xt = (bid>>2) % 3; int yt = (bid/12) % 24; int b = bid/288;
  int c0 = ct*32, x0 = xt*32, y0 = yt*4;
  int t = threadIdx.x;
  for (int yy=0; yy<4; ++yy){
    int y = y0 + yy;
    #pragma unroll
    for (int rep=0; rep<4; ++rep){
      int idx = rep*256 + t;
      int ci = idx >> 5, xj = idx & 31;
      lds[ci][xj] = x[((b*CIN + c0+ci)*HW + y)*HW + x0 + xj];
    }
    __syncthreads();
    int px = t >> 3, quad = t & 7;
    ushortx4 v;
    #pragma unroll
    for (int k=0;k<4;k++) v[k] = f2bf(lds[quad*4+k][px]);
    *(ushortx4*)&xpad[(((b*HP + y+1)*HP) + x0+px+1)*CIN + c0 + quad*4] = v;
    __syncthreads();
  }
}

// w1 [256][128][3][3] fp32 -> w1t [256][1152] bf16, k = tap*128 + c
__global__ void transform_w1(const float* __restrict__ w1, ushort_t* __restrict__ w1t){
  int tid = blockIdx.x*256 + threadIdx.x;   // 294912 exact
  int o = tid / 1152, k = tid - o*1152;
  int tap = k >> 7, c = k & 127;
  w1t[tid] = f2bf(w1[(o*CIN + c)*9 + tap]);
}

// w2 [2][256][3][3] fp32 -> w2t [9][256][2] fp32
__global__ void transform_w2(const float* __restrict__ w2, float* __restrict__ w2t){
  int tid = blockIdx.x*256 + threadIdx.x;
  if (tid >= 4608) return;
  int ch = tid & 1, c = (tid >> 1) & 255, tap = tid >> 9;
  w2t[tid] = w2[(ch*CH + c)*9 + tap];
}

// ---------------------------------------------------------------------------
// conv1 v3: implicit GEMM, M=256 x N=147456 x K=1152. BM=256, BN=192 (6y x 32x),
// BK=64 -> 18 K-tiles. 512 thr / 8 waves (2M x 4N), per-wave 128x48 (acc[8][3]).
// Grid = 768 blocks = exactly 3 rounds of 256 CUs (zero tail). LDS 136 KB:
// A double-buffered (2x32KB, staged 1 ahead), B triple-buffered (3x24KB, 2 ahead).
// T2 swizzle: stored octet = logical ^ (row&7) on 128B rows; gload_lds source
// pre-swizzled, ds_read XOR'd (same involution both sides — conv2-proven).
// Ledger (per wave, 7 stage-instr/K-tile, order A(4) then B(3)):
//   entry of kt: outstanding = [B-kt(3)][A-kt(4)][B-kt+1(3)] -> vmcnt(3)
//   guarantees kt's A and B landed, keeps B-kt+1 in flight. One s_barrier/K-tile.
//   WAR: stage targets were last read in kt-1; reads complete (lgkmcnt before
//   MFMA use) before the entry barrier of kt -> safe. kt=17 peeled, vmcnt(0).
// ---------------------------------------------------------------------------
#define C1_TILE(KT, VMN, SB) { \
  asm volatile("s_waitcnt vmcnt(" #VMN ")" ::: "memory"); \
  __builtin_amdgcn_s_barrier(); \
  __builtin_amdgcn_sched_barrier(0); \
  const int kt_ = (KT); \
  { const int ka_ = kt_ + 1; \
    if (ka_ < 18) { \
      const int ab_ = (ka_ & 1) * 16384; \
      _Pragma("unroll") \
      for (int j=0;j<4;++j) \
        async_ld16(&Alds[ab_ + j*4096 + adst], &w1t[asrc + j*73728 + ka_*64]); \
    } } \
  if (SB) { \
    const int kb_ = kt_ + 2; \
    const int tapb_ = kb_ >> 1; \
    const int dyb_ = tapb_/3; const int dxb_ = tapb_ - dyb_*3; \
    const int bdb_ = (dyb_*HP + dxb_)*CIN + (kb_&1)*64; \
    const int bb_ = (kb_ % 3) * 12288; \
    _Pragma("unroll") \
    for (int j=0;j<3;++j) \
      async_ld16(&Blds[bb_ + j*4096 + bdst], &xpad[bsrc + j*(2*HP*CIN) + bdb_]); \
  } \
  const ushort_t* Ab = &Alds[(kt_ & 1) * 16384]; \
  const ushort_t* Bb = &Blds[(kt_ % 3) * 12288]; \
  short8 bb0[3], aa0[4], aa1[4], bb1[3], cc0[4], cc1[4]; \
  _Pragma("unroll") \
  for (int nf=0; nf<3; ++nf) bb0[nf] = *(const short8*)&Bb[bbase_r + nf*1024 + koff0]; \
  _Pragma("unroll") \
  for (int mf=0; mf<4; ++mf) aa0[mf] = *(const short8*)&Ab[abase_r + mf*1024 + koff0]; \
  _Pragma("unroll") \
  for (int mf=0; mf<4; ++mf) aa1[mf] = *(const short8*)&Ab[abase_r + (mf+4)*1024 + koff0]; \
  __builtin_amdgcn_s_setprio(1); \
  _Pragma("unroll") \
  for (int mf=0; mf<4; ++mf) \
    _Pragma("unroll") \
    for (int nf=0; nf<3; ++nf) \
      acc[mf][nf] = __builtin_amdgcn_mfma_f32_16x16x32_bf16(aa0[mf], bb0[nf], acc[mf][nf], 0,0,0); \
  __builtin_amdgcn_s_setprio(0); \
  _Pragma("unroll") \
  for (int nf=0; nf<3; ++nf) bb1[nf] = *(const short8*)&Bb[bbase_r + nf*1024 + koff1]; \
  _Pragma("unroll") \
  for (int mf=0; mf<4; ++mf) cc0[mf] = *(const short8*)&Ab[abase_r + mf*1024 + koff1]; \
  __builtin_amdgcn_s_setprio(1); \
  _Pragma("unroll") \
  for (int mf=0; mf<4; ++mf) \
    _Pragma("unroll") \
    for (int nf=0; nf<3; ++nf) \
      acc[mf+4][nf] = __builtin_amdgcn_mfma_f32_16x16x32_bf16(aa1[mf], bb0[nf], acc[mf+4][nf], 0,0,0); \
  __builtin_amdgcn_s_setprio(0); \
  _Pragma("unroll") \
  for (int mf=0; mf<4; ++mf) cc1[mf] = *(const short8*)&Ab[abase_r + (mf+4)*1024 + koff1]; \
  __builtin_amdgcn_s_setprio(1); \
  _Pragma("unroll") \
  for (int mf=0; mf<4; ++mf) \
    _Pragma("unroll") \
    for (int nf=0; nf<3; ++nf) \
      acc[mf][nf] = __builtin_amdgcn_mfma_f32_16x16x32_bf16(cc0[mf], bb1[nf], acc[mf][nf], 0,0,0); \
  _Pragma("unroll") \
  for (int mf=0; mf<4; ++mf) \
    _Pragma("unroll") \
    for (int nf=0; nf<3; ++nf) \
      acc[mf+4][nf] = __builtin_amdgcn_mfma_f32_16x16x32_bf16(cc1[mf], bb1[nf], acc[mf+4][nf], 0,0,0); \
  __builtin_amdgcn_s_setprio(0); \
}

__global__ __launch_bounds__(512, 1) void conv1(const ushort_t* __restrict__ xpad,
                                                const ushort_t* __restrict__ w1t,
                                                const float* __restrict__ b1,
                                                ushort_t* __restrict__ hpad){
  __shared__ __align__(16) ushort_t Alds[2*16384];   // 2 bufs x 256 rows x 64 (64 KB)
  __shared__ __align__(16) ushort_t Blds[3*12288];   // 3 bufs x 192 rows x 64 (72 KB)
  int orig = blockIdx.x;
  int bid = (orig & 7) * 96 + (orig >> 3);           // XCD swizzle, 768 % 8 == 0
  int b = bid / 48; int rem = bid - b*48;
  int y0 = (rem/3)*6, x0 = (rem - (rem/3)*3)*32;     // 6y x 32x pixel tile
  int t = threadIdx.x;
  int lane = t & 63, wave = t >> 6;
  int wm = wave & 1, wn = wave >> 1;                 // 2M x 4N waves
  int r = lane & 15, q = lane >> 4;

  // staging maps (granule v = j*512 + t; row = v>>3; stored oct = v&7 holds
  // logical oct (v&7)^(row&7) -> source pre-swizzled, LDS dest linear)
  const int arow0 = t >> 3;                          // 0..63 (j adds 64 each)
  const int soct  = (t & 7) ^ (arow0 & 7);           // same for all j (64%8==0)
  const int adst  = t * 8;                           // + j*4096 + buf*16384
  const int asrc  = arow0 * 1152 + soct * 8;         // + j*73728 + kt*64
  const int bty0  = arow0 >> 5, btx0 = arow0 & 31;   // B row = pixel index
  const int bdst  = t * 8;                           // + j*4096 + buf*12288
  const int bsrc  = ((b*HP + y0 + bty0)*HP + x0 + btx0)*CIN + soct * 8; // + j*2*HP*CIN + bd

  // fragment read offsets (ushort units); row&7 == r&7 for all frag rows
  const int koff0 = ((0*4 + q) ^ (r & 7)) * 8;
  const int koff1 = ((1*4 + q) ^ (r & 7)) * 8;
  const int abase_r = (wm*128 + r) * 64;             // + mf*1024
  const int bbase_r = (wn*48  + r) * 64;             // + nf*1024

  floatx4 acc[8][3];
  #pragma unroll
  for (int i=0;i<8;i++)
    #pragma unroll
    for (int j=0;j<3;j++) acc[i][j] = (floatx4){0.f,0.f,0.f,0.f};

  // prologue: ledger order B-for-0(3), A-for-0(4), B-for-1(3)
  #pragma unroll
  for (int j=0;j<3;++j) async_ld16(&Blds[0     + j*4096 + bdst], &xpad[bsrc + j*(2*HP*CIN)]);
  #pragma unroll
  for (int j=0;j<4;++j) async_ld16(&Alds[0     + j*4096 + adst], &w1t[asrc + j*73728]);
  #pragma unroll
  for (int j=0;j<3;++j) async_ld16(&Blds[12288 + j*4096 + bdst], &xpad[bsrc + j*(2*HP*CIN) + 64]);

  for (int kt=0; kt<16; ++kt){
    C1_TILE(kt, 3, 1)
  }
  C1_TILE(16, 3, 0)
  C1_TILE(17, 0, 0)

  // epilogue: +bias, ReLU, bf16, store padded NHWC h
  #pragma unroll
  for (int mf=0; mf<8; ++mf){
    int o = wm*128 + mf*16 + q*4;
    float bias0 = b1[o], bias1 = b1[o+1], bias2 = b1[o+2], bias3 = b1[o+3];
    #pragma unroll
    for (int nf=0; nf<3; ++nf){
      int n = wn*48 + nf*16 + r;
      int ty = n >> 5, tx = n & 31;
      ushortx4 v;
      v[0] = f2bf(fmaxf(acc[mf][nf][0] + bias0, 0.f));
      v[1] = f2bf(fmaxf(acc[mf][nf][1] + bias1, 0.f));
      v[2] = f2bf(fmaxf(acc[mf][nf][2] + bias2, 0.f));
      v[3] = f2bf(fmaxf(acc[mf][nf][3] + bias3, 0.f));
      *(ushortx4*)&hpad[((b*HP + y0+ty+1)*HP + (x0+tx+1))*CH + o] = v;
    }
  }
}

// conv2: LDS-staged direct 3x3. Block = 8x8 output tile, halo 10x10 cells x 512B
// staged into LDS (51.2 KB) via global_load_lds: LDS dest linear, global SOURCE
// pre-swizzled chunk ^ (cell&7); reads apply the same XOR (both-sides involution).
// Wave = channel quarter (w addresses wave-uniform -> scalar cache); lane = pixel.
__global__ __launch_bounds__(256) void conv2(const ushort_t* __restrict__ hpad,
                                             const float* __restrict__ w2t,
                                             const float* __restrict__ b2,
                                             float* __restrict__ out){
  __shared__ __align__(16) ushort_t hlds[25600];   // 100 cells * 256 ushorts
  __shared__ float part[4][64][2];
  int bid = blockIdx.x;              // 2304 = 16 b * 12 yt * 12 xt
  int b = bid / 144; int rem = bid - b*144;
  int yt = rem / 12, xt = rem - yt*12;
  int y0 = yt*8, x0 = xt*8;          // padded window base = (y0, x0)
  int t = threadIdx.x;
  int wave = t >> 6, lane = t & 63;

  // stage 3200 x 16B chunks, pre-swizzled source
  for (int pass=0; pass<13; ++pass){
    int u = pass*256 + t;
    if (u < 3200){
      int cell = u >> 5, cf = u & 31;
      int hy = cell / 10, hx = cell - hy*10;
      const ushort_t* src = hpad + ((b*HP + y0+hy)*HP + (x0+hx))*CH
                                 + ((cf ^ (cell & 7)) << 3);
      async_ld16(&hlds[(pass*256 + wave*64)*8], src);
    }
  }
  __syncthreads();

  int q = __builtin_amdgcn_readfirstlane(wave);    // channel quarter, provably uniform
  int ty = lane >> 3, tx = lane & 7;
  float a0 = 0.f, a1 = 0.f;
  for (int tap=0; tap<9; ++tap){
    int dy = tap/3, dxx = tap - dy*3;
    int cell = (ty+dy)*10 + (tx+dxx);
    int s = cell & 7;
    const float* wp = w2t + (tap*256 + q*64)*2;    // scalar pointer
    #pragma unroll
    for (int g=0; g<8; ++g){
      int j = q*8 + g;
      ushortx8 hv = *(const ushortx8*)&hlds[cell*256 + ((j ^ s) << 3)];
      #pragma unroll
      for (int i=0;i<8;i++){
        float hf = bf2f(hv[i]);
        a0 = fmaf(hf, wp[(g*8+i)*2    ], a0);
        a1 = fmaf(hf, wp[(g*8+i)*2 + 1], a1);
      }
    }
  }
  part[wave][lane][0] = a0;
  part[wave][lane][1] = a1;
  __syncthreads();
  if (t < 128){
    int sel = t >> 6, pix = t & 63;
    float v = part[0][pix][sel] + part[1][pix][sel]
            + part[2][pix][sel] + part[3][pix][sel] + b2[sel];
    int yy = y0 + (pix >> 3), xx = x0 + (pix & 7);
    out[(b*2 + sel)*9216 + yy*96 + xx] = v;
  }
}

extern "C" void kernel_launch(void* const* d_in, const int* in_sizes, int n_in,
                              void* d_out, int out_size, void* d_ws, size_t ws_size,
                              hipStream_t stream){
  const float* x  = (const float*)d_in[0];
  const float* w1 = (const float*)d_in[1];
  const float* b1 = (const float*)d_in[2];
  const float* w2 = (const float*)d_in[3];
  const float* b2 = (const float*)d_in[4];
  float* out = (float*)d_out;
  char* ws = (char*)d_ws;
  ushort_t* xpad = (ushort_t*)(ws + XPAD_OFF);
  ushort_t* hpad = (ushort_t*)(ws + HPAD_OFF);
  ushort_t* w1t  = (ushort_t*)(ws + W1T_OFF);
  float*    w2t  = (float*)(ws + W2T_OFF);

  hipLaunchKernelGGL(zero_border, dim3(16*388*64/256),  dim3(256), 0, stream, (uint32_t*)xpad, 64);
  hipLaunchKernelGGL(zero_border, dim3(16*388*128/256), dim3(256), 0, stream, (uint32_t*)hpad, 128);
  hipLaunchKernelGGL(transform_x,  dim3(4608),  dim3(256), 0, stream, x, xpad);
  hipLaunchKernelGGL(transform_w1, dim3(1152),  dim3(256), 0, stream, w1, w1t);
  hipLaunchKernelGGL(transform_w2, dim3(18),    dim3(256), 0, stream, w2, w2t);
  hipLaunchKernelGGL(conv1, dim3(768),  dim3(512), 0, stream, xpad, w1t, b1, hpad);
  hipLaunchKernelGGL(conv2, dim3(2304), dim3(256), 0, stream, hpad, w2t, b2, out);
}

// Round 7
// 174.526 us; speedup vs baseline: 1.3504x; 1.0159x over previous
//
#include <hip/hip_runtime.h>
#include <stdint.h>

typedef unsigned short ushort_t;
typedef __attribute__((ext_vector_type(8))) short short8;
typedef __attribute__((ext_vector_type(4))) float floatx4;
typedef __attribute__((ext_vector_type(4))) unsigned short ushortx4;
typedef __attribute__((ext_vector_type(8))) unsigned short ushortx8;

#define B_   16
#define CIN  128
#define CH   256
#define HW   96
#define HP   98

// ws layout (bytes)
#define XPAD_ELEMS (B_*HP*HP*CIN)            // bf16 elems
#define HPAD_ELEMS (B_*HP*HP*CH)             // bf16 elems
#define XPAD_OFF 0
#define HPAD_OFF (XPAD_ELEMS*2)
#define W1T_OFF  (HPAD_OFF + HPAD_ELEMS*2)
#define W2T_OFF  (W1T_OFF + 256*1152*2)

__device__ __forceinline__ ushort_t f2bf(float f){
  uint32_t u = __float_as_uint(f);
  u += 0x7FFF + ((u >> 16) & 1);   // RNE
  return (ushort_t)(u >> 16);
}
__device__ __forceinline__ float bf2f(ushort_t h){
  return __uint_as_float(((uint32_t)h) << 16);
}
__device__ __forceinline__ void async_ld16(void* lds, const void* g){
  __builtin_amdgcn_global_load_lds(
      (const __attribute__((address_space(1))) void*)g,
      (__attribute__((address_space(3))) void*)lds, 16, 0, 0);
}

// Zero the 1-px border cells of a padded NHWC tensor. C2 = channels/2 (uint32 words per cell).
__global__ void zero_border(uint32_t* __restrict__ base, int C2){
  int tid = blockIdx.x*256 + threadIdx.x;
  int perimg = 388*C2;
  int total = B_*perimg;
  if (tid >= total) return;
  int b = tid / perimg; int r = tid % perimg;
  int cell = r / C2;    int cu = r % C2;
  int y, x;
  if      (cell < 98)  { y = 0;            x = cell;       }
  else if (cell < 196) { y = 97;           x = cell - 98;  }
  else if (cell < 292) { y = cell - 195;   x = 0;          }
  else                 { y = cell - 291;   x = 97;         }
  base[((b*HP + y)*HP + x)*C2 + cu] = 0u;
}

// NCHW fp32 -> padded NHWC bf16 via LDS transpose. One block = (b, 4 y-rows, 32x, 32c).
__global__ void transform_x(const float* __restrict__ x, ushort_t* __restrict__ xpad){
  __shared__ float lds[32][33];
  int bid = blockIdx.x;              // 4608 = 16 b * 24 yt * 3 xt * 4 ct
  int ct = bid & 3; int xt = (bid>>2) % 3; int yt = (bid/12) % 24; int b = bid/288;
  int c0 = ct*32, x0 = xt*32, y0 = yt*4;
  int t = threadIdx.x;
  for (int yy=0; yy<4; ++yy){
    int y = y0 + yy;
    #pragma unroll
    for (int rep=0; rep<4; ++rep){
      int idx = rep*256 + t;
      int ci = idx >> 5, xj = idx & 31;
      lds[ci][xj] = x[((b*CIN + c0+ci)*HW + y)*HW + x0 + xj];
    }
    __syncthreads();
    int px = t >> 3, quad = t & 7;
    ushortx4 v;
    #pragma unroll
    for (int k=0;k<4;k++) v[k] = f2bf(lds[quad*4+k][px]);
    *(ushortx4*)&xpad[(((b*HP + y+1)*HP) + x0+px+1)*CIN + c0 + quad*4] = v;
    __syncthreads();
  }
}

// w1 [256][128][3][3] fp32 -> w1t [256][1152] bf16, k = tap*128 + c
__global__ void transform_w1(const float* __restrict__ w1, ushort_t* __restrict__ w1t){
  int tid = blockIdx.x*256 + threadIdx.x;   // 294912 exact
  int o = tid / 1152, k = tid - o*1152;
  int tap = k >> 7, c = k & 127;
  w1t[tid] = f2bf(w1[(o*CIN + c)*9 + tap]);
}

// w2 [2][256][3][3] fp32 -> w2t [9][256][2] fp32
__global__ void transform_w2(const float* __restrict__ w2, float* __restrict__ w2t){
  int tid = blockIdx.x*256 + threadIdx.x;
  if (tid >= 4608) return;
  int ch = tid & 1, c = (tid >> 1) & 255, tap = tid >> 9;
  w2t[tid] = w2[(ch*CH + c)*9 + tap];
}

// ---------------------------------------------------------------------------
// conv1 v4: geometry/buffers/ledger identical to v3 (BM=256, BN=192, BK=64,
// 18 K-tiles, 8 waves 2Mx4N, A 2-buf / B 3-buf, T2 both-sides swizzle,
// vmcnt(3) once per K-tile — never drains until the peeled kt=17).
// NEW: m201-style 4-phase interleave per K-tile. Each phase:
//   {ds_read subtile || issue 1-2 gload_lds} -> s_barrier -> lgkmcnt(0) ->
//   setprio(1) -> 12 MFMA -> setprio(0) -> s_barrier
// Accumulation order per acc element unchanged (kk0 then kk1 per kt) ->
// output must stay bit-identical (absmax 0.015625).
// ---------------------------------------------------------------------------
#define C1_TILE(KT, VMN, SA, SB) { \
  asm volatile("s_waitcnt vmcnt(" #VMN ")" ::: "memory"); \
  __builtin_amdgcn_s_barrier(); \
  __builtin_amdgcn_sched_barrier(0); \
  const int kt_ = (KT); \
  const ushort_t* Ab = &Alds[(kt_ & 1) * 16384]; \
  const ushort_t* Bb = &Blds[(kt_ % 3) * 12288]; \
  short8 aa0[4], aa1[4], bb0[3], bb1[3], cc0[4], cc1[4]; \
  /* ---- P0: A[0..3]@k0 + B@k0 ; stage A(kt+1) j0,j1 ---- */ \
  _Pragma("unroll") \
  for (int nf=0; nf<3; ++nf) bb0[nf] = *(const short8*)&Bb[bbase_r + nf*1024 + koff0]; \
  _Pragma("unroll") \
  for (int mf=0; mf<4; ++mf) aa0[mf] = *(const short8*)&Ab[abase_r + mf*1024 + koff0]; \
  if (SA) { \
    const int ka_ = kt_ + 1; const int ab_ = (ka_ & 1) * 16384; \
    async_ld16(&Alds[ab_ +     0 + adst], &w1t[asrc +       0 + ka_*64]); \
    async_ld16(&Alds[ab_ +  4096 + adst], &w1t[asrc +   73728 + ka_*64]); \
  } \
  __builtin_amdgcn_s_barrier(); \
  asm volatile("s_waitcnt lgkmcnt(0)" ::: "memory"); \
  __builtin_amdgcn_sched_barrier(0); \
  __builtin_amdgcn_s_setprio(1); \
  _Pragma("unroll") \
  for (int mf=0; mf<4; ++mf) \
    _Pragma("unroll") \
    for (int nf=0; nf<3; ++nf) \
      acc[mf][nf] = __builtin_amdgcn_mfma_f32_16x16x32_bf16(aa0[mf], bb0[nf], acc[mf][nf], 0,0,0); \
  __builtin_amdgcn_s_setprio(0); \
  __builtin_amdgcn_s_barrier(); \
  /* ---- P1: A[4..7]@k0 ; stage A(kt+1) j2,j3 ---- */ \
  _Pragma("unroll") \
  for (int mf=0; mf<4; ++mf) aa1[mf] = *(const short8*)&Ab[abase_r + (mf+4)*1024 + koff0]; \
  if (SA) { \
    const int ka_ = kt_ + 1; const int ab_ = (ka_ & 1) * 16384; \
    async_ld16(&Alds[ab_ +  8192 + adst], &w1t[asrc + 2*73728 + ka_*64]); \
    async_ld16(&Alds[ab_ + 12288 + adst], &w1t[asrc + 3*73728 + ka_*64]); \
  } \
  __builtin_amdgcn_s_barrier(); \
  asm volatile("s_waitcnt lgkmcnt(0)" ::: "memory"); \
  __builtin_amdgcn_sched_barrier(0); \
  __builtin_amdgcn_s_setprio(1); \
  _Pragma("unroll") \
  for (int mf=0; mf<4; ++mf) \
    _Pragma("unroll") \
    for (int nf=0; nf<3; ++nf) \
      acc[mf+4][nf] = __builtin_amdgcn_mfma_f32_16x16x32_bf16(aa1[mf], bb0[nf], acc[mf+4][nf], 0,0,0); \
  __builtin_amdgcn_s_setprio(0); \
  __builtin_amdgcn_s_barrier(); \
  /* ---- P2: A[0..3]@k1 + B@k1 ; stage B(kt+2) j0,j1 ---- */ \
  _Pragma("unroll") \
  for (int nf=0; nf<3; ++nf) bb1[nf] = *(const short8*)&Bb[bbase_r + nf*1024 + koff1]; \
  _Pragma("unroll") \
  for (int mf=0; mf<4; ++mf) cc0[mf] = *(const short8*)&Ab[abase_r + mf*1024 + koff1]; \
  if (SB) { \
    const int kb_ = kt_ + 2; \
    const int tapb_ = kb_ >> 1; \
    const int dyb_ = tapb_/3; const int dxb_ = tapb_ - dyb_*3; \
    const int bdb_ = (dyb_*HP + dxb_)*CIN + (kb_&1)*64; \
    const int bb_ = (kb_ % 3) * 12288; \
    async_ld16(&Blds[bb_ +    0 + bdst], &xpad[bsrc +            bdb_]); \
    async_ld16(&Blds[bb_ + 4096 + bdst], &xpad[bsrc + 2*HP*CIN + bdb_]); \
  } \
  __builtin_amdgcn_s_barrier(); \
  asm volatile("s_waitcnt lgkmcnt(0)" ::: "memory"); \
  __builtin_amdgcn_sched_barrier(0); \
  __builtin_amdgcn_s_setprio(1); \
  _Pragma("unroll") \
  for (int mf=0; mf<4; ++mf) \
    _Pragma("unroll") \
    for (int nf=0; nf<3; ++nf) \
      acc[mf][nf] = __builtin_amdgcn_mfma_f32_16x16x32_bf16(cc0[mf], bb1[nf], acc[mf][nf], 0,0,0); \
  __builtin_amdgcn_s_setprio(0); \
  __builtin_amdgcn_s_barrier(); \
  /* ---- P3: A[4..7]@k1 ; stage B(kt+2) j2 ---- */ \
  _Pragma("unroll") \
  for (int mf=0; mf<4; ++mf) cc1[mf] = *(const short8*)&Ab[abase_r + (mf+4)*1024 + koff1]; \
  if (SB) { \
    const int kb_ = kt_ + 2; \
    const int tapb_ = kb_ >> 1; \
    const int dyb_ = tapb_/3; const int dxb_ = tapb_ - dyb_*3; \
    const int bdb_ = (dyb_*HP + dxb_)*CIN + (kb_&1)*64; \
    const int bb_ = (kb_ % 3) * 12288; \
    async_ld16(&Blds[bb_ + 8192 + bdst], &xpad[bsrc + 4*HP*CIN + bdb_]); \
  } \
  __builtin_amdgcn_s_barrier(); \
  asm volatile("s_waitcnt lgkmcnt(0)" ::: "memory"); \
  __builtin_amdgcn_sched_barrier(0); \
  __builtin_amdgcn_s_setprio(1); \
  _Pragma("unroll") \
  for (int mf=0; mf<4; ++mf) \
    _Pragma("unroll") \
    for (int nf=0; nf<3; ++nf) \
      acc[mf+4][nf] = __builtin_amdgcn_mfma_f32_16x16x32_bf16(cc1[mf], bb1[nf], acc[mf+4][nf], 0,0,0); \
  __builtin_amdgcn_s_setprio(0); \
}

__global__ __launch_bounds__(512, 1) void conv1(const ushort_t* __restrict__ xpad,
                                                const ushort_t* __restrict__ w1t,
                                                const float* __restrict__ b1,
                                                ushort_t* __restrict__ hpad){
  __shared__ __align__(16) ushort_t Alds[2*16384];   // 2 bufs x 256 rows x 64 (64 KB)
  __shared__ __align__(16) ushort_t Blds[3*12288];   // 3 bufs x 192 rows x 64 (72 KB)
  int orig = blockIdx.x;
  int bid = (orig & 7) * 96 + (orig >> 3);           // XCD swizzle, 768 % 8 == 0
  int b = bid / 48; int rem = bid - b*48;
  int y0 = (rem/3)*6, x0 = (rem - (rem/3)*3)*32;     // 6y x 32x pixel tile
  int t = threadIdx.x;
  int lane = t & 63, wave = t >> 6;
  int wm = wave & 1, wn = wave >> 1;                 // 2M x 4N waves
  int r = lane & 15, q = lane >> 4;

  // staging maps (granule v = j*512 + t; row = v>>3; stored oct = v&7 holds
  // logical oct (v&7)^(row&7) -> source pre-swizzled, LDS dest linear)
  const int arow0 = t >> 3;                          // 0..63 (j adds 64 each)
  const int soct  = (t & 7) ^ (arow0 & 7);           // same for all j (64%8==0)
  const int adst  = t * 8;                           // + j*4096 + buf*16384
  const int asrc  = arow0 * 1152 + soct * 8;         // + j*73728 + kt*64
  const int bty0  = arow0 >> 5, btx0 = arow0 & 31;   // B row = pixel index
  const int bdst  = t * 8;                           // + j*4096 + buf*12288
  const int bsrc  = ((b*HP + y0 + bty0)*HP + x0 + btx0)*CIN + soct * 8; // + j*2*HP*CIN + bd

  // fragment read offsets (ushort units); row&7 == r&7 for all frag rows
  const int koff0 = ((0*4 + q) ^ (r & 7)) * 8;
  const int koff1 = ((1*4 + q) ^ (r & 7)) * 8;
  const int abase_r = (wm*128 + r) * 64;             // + mf*1024
  const int bbase_r = (wn*48  + r) * 64;             // + nf*1024

  floatx4 acc[8][3];
  #pragma unroll
  for (int i=0;i<8;i++)
    #pragma unroll
    for (int j=0;j<3;j++) acc[i][j] = (floatx4){0.f,0.f,0.f,0.f};

  // prologue: ledger order B-for-0(3), A-for-0(4), B-for-1(3)
  #pragma unroll
  for (int j=0;j<3;++j) async_ld16(&Blds[0     + j*4096 + bdst], &xpad[bsrc + j*(2*HP*CIN)]);
  #pragma unroll
  for (int j=0;j<4;++j) async_ld16(&Alds[0     + j*4096 + adst], &w1t[asrc + j*73728]);
  #pragma unroll
  for (int j=0;j<3;++j) async_ld16(&Blds[12288 + j*4096 + bdst], &xpad[bsrc + j*(2*HP*CIN) + 64]);

  for (int kt=0; kt<16; ++kt){
    C1_TILE(kt, 3, 1, 1)
  }
  C1_TILE(16, 3, 1, 0)
  C1_TILE(17, 0, 0, 0)

  // epilogue: +bias, ReLU, bf16, store padded NHWC h
  #pragma unroll
  for (int mf=0; mf<8; ++mf){
    int o = wm*128 + mf*16 + q*4;
    float bias0 = b1[o], bias1 = b1[o+1], bias2 = b1[o+2], bias3 = b1[o+3];
    #pragma unroll
    for (int nf=0; nf<3; ++nf){
      int n = wn*48 + nf*16 + r;
      int ty = n >> 5, tx = n & 31;
      ushortx4 v;
      v[0] = f2bf(fmaxf(acc[mf][nf][0] + bias0, 0.f));
      v[1] = f2bf(fmaxf(acc[mf][nf][1] + bias1, 0.f));
      v[2] = f2bf(fmaxf(acc[mf][nf][2] + bias2, 0.f));
      v[3] = f2bf(fmaxf(acc[mf][nf][3] + bias3, 0.f));
      *(ushortx4*)&hpad[((b*HP + y0+ty+1)*HP + (x0+tx+1))*CH + o] = v;
    }
  }
}

// conv2: LDS-staged direct 3x3. Block = 8x8 output tile, halo 10x10 cells x 512B
// staged into LDS (51.2 KB) via global_load_lds: LDS dest linear, global SOURCE
// pre-swizzled chunk ^ (cell&7); reads apply the same XOR (both-sides involution).
// Wave = channel quarter (w addresses wave-uniform -> scalar cache); lane = pixel.
__global__ __launch_bounds__(256) void conv2(const ushort_t* __restrict__ hpad,
                                             const float* __restrict__ w2t,
                                             const float* __restrict__ b2,
                                             float* __restrict__ out){
  __shared__ __align__(16) ushort_t hlds[25600];   // 100 cells * 256 ushorts
  __shared__ float part[4][64][2];
  int bid = blockIdx.x;              // 2304 = 16 b * 12 yt * 12 xt
  int b = bid / 144; int rem = bid - b*144;
  int yt = rem / 12, xt = rem - yt*12;
  int y0 = yt*8, x0 = xt*8;          // padded window base = (y0, x0)
  int t = threadIdx.x;
  int wave = t >> 6, lane = t & 63;

  // stage 3200 x 16B chunks, pre-swizzled source
  for (int pass=0; pass<13; ++pass){
    int u = pass*256 + t;
    if (u < 3200){
      int cell = u >> 5, cf = u & 31;
      int hy = cell / 10, hx = cell - hy*10;
      const ushort_t* src = hpad + ((b*HP + y0+hy)*HP + (x0+hx))*CH
                                 + ((cf ^ (cell & 7)) << 3);
      async_ld16(&hlds[(pass*256 + wave*64)*8], src);
    }
  }
  __syncthreads();

  int q = __builtin_amdgcn_readfirstlane(wave);    // channel quarter, provably uniform
  int ty = lane >> 3, tx = lane & 7;
  float a0 = 0.f, a1 = 0.f;
  for (int tap=0; tap<9; ++tap){
    int dy = tap/3, dxx = tap - dy*3;
    int cell = (ty+dy)*10 + (tx+dxx);
    int s = cell & 7;
    const float* wp = w2t + (tap*256 + q*64)*2;    // scalar pointer
    #pragma unroll
    for (int g=0; g<8; ++g){
      int j = q*8 + g;
      ushortx8 hv = *(const ushortx8*)&hlds[cell*256 + ((j ^ s) << 3)];
      #pragma unroll
      for (int i=0;i<8;i++){
        float hf = bf2f(hv[i]);
        a0 = fmaf(hf, wp[(g*8+i)*2    ], a0);
        a1 = fmaf(hf, wp[(g*8+i)*2 + 1], a1);
      }
    }
  }
  part[wave][lane][0] = a0;
  part[wave][lane][1] = a1;
  __syncthreads();
  if (t < 128){
    int sel = t >> 6, pix = t & 63;
    float v = part[0][pix][sel] + part[1][pix][sel]
            + part[2][pix][sel] + part[3][pix][sel] + b2[sel];
    int yy = y0 + (pix >> 3), xx = x0 + (pix & 7);
    out[(b*2 + sel)*9216 + yy*96 + xx] = v;
  }
}

extern "C" void kernel_launch(void* const* d_in, const int* in_sizes, int n_in,
                              void* d_out, int out_size, void* d_ws, size_t ws_size,
                              hipStream_t stream){
  const float* x  = (const float*)d_in[0];
  const float* w1 = (const float*)d_in[1];
  const float* b1 = (const float*)d_in[2];
  const float* w2 = (const float*)d_in[3];
  const float* b2 = (const float*)d_in[4];
  float* out = (float*)d_out;
  char* ws = (char*)d_ws;
  ushort_t* xpad = (ushort_t*)(ws + XPAD_OFF);
  ushort_t* hpad = (ushort_t*)(ws + HPAD_OFF);
  ushort_t* w1t  = (ushort_t*)(ws + W1T_OFF);
  float*    w2t  = (float*)(ws + W2T_OFF);

  hipLaunchKernelGGL(zero_border, dim3(16*388*64/256),  dim3(256), 0, stream, (uint32_t*)xpad, 64);
  hipLaunchKernelGGL(zero_border, dim3(16*388*128/256), dim3(256), 0, stream, (uint32_t*)hpad, 128);
  hipLaunchKernelGGL(transform_x,  dim3(4608),  dim3(256), 0, stream, x, xpad);
  hipLaunchKernelGGL(transform_w1, dim3(1152),  dim3(256), 0, stream, w1, w1t);
  hipLaunchKernelGGL(transform_w2, dim3(18),    dim3(256), 0, stream, w2, w2t);
  hipLaunchKernelGGL(conv1, dim3(768),  dim3(512), 0, stream, xpad, w1t, b1, hpad);
  hipLaunchKernelGGL(conv2, dim3(2304), dim3(256), 0, stream, hpad, w2t, b2, out);
}

// Round 8
// 160.399 us; speedup vs baseline: 1.4694x; 1.0881x over previous
//
#include <hip/hip_runtime.h>
#include <stdint.h>

typedef unsigned short ushort_t;
typedef __attribute__((ext_vector_type(8))) short short8;
typedef __attribute__((ext_vector_type(4))) float floatx4;
typedef __attribute__((ext_vector_type(4))) unsigned short ushortx4;
typedef __attribute__((ext_vector_type(8))) unsigned short ushortx8;

#define B_   16
#define CIN  128
#define CH   256
#define HW   96
#define HP   98

// ws layout (bytes)
#define XPAD_ELEMS (B_*HP*HP*CIN)            // bf16 elems
#define HPAD_ELEMS (B_*HP*HP*CH)             // bf16 elems
#define XPAD_OFF 0
#define HPAD_OFF (XPAD_ELEMS*2)
#define W1T_OFF  (HPAD_OFF + HPAD_ELEMS*2)
#define W2T_OFF  (W1T_OFF + 256*1152*2)

__device__ __forceinline__ ushort_t f2bf(float f){
  uint32_t u = __float_as_uint(f);
  u += 0x7FFF + ((u >> 16) & 1);   // RNE
  return (ushort_t)(u >> 16);
}
__device__ __forceinline__ float bf2f(ushort_t h){
  return __uint_as_float(((uint32_t)h) << 16);
}
__device__ __forceinline__ void async_ld16(void* lds, const void* g){
  __builtin_amdgcn_global_load_lds(
      (const __attribute__((address_space(1))) void*)g,
      (__attribute__((address_space(3))) void*)lds, 16, 0, 0);
}

// Zero one border word of a padded NHWC tensor. C2 = channels/2 (u32 words/cell).
__device__ __forceinline__ void zb(uint32_t* base, int C2, int tid){
  int perimg = 388*C2;
  int b = tid / perimg; int r = tid % perimg;
  int cell = r / C2;    int cu = r % C2;
  int y, x;
  if      (cell < 98)  { y = 0;            x = cell;       }
  else if (cell < 196) { y = 97;           x = cell - 98;  }
  else if (cell < 292) { y = cell - 195;   x = 0;          }
  else                 { y = cell - 291;   x = 97;         }
  base[((b*HP + y)*HP + x)*C2 + cu] = 0u;
}

// Fused small prep: xpad borders, hpad borders, w1 transform, w2 transform.
// Segments are disjoint writes; total units = 397312+794624+294912+4608 = 1491456 = 5826*256.
__global__ __launch_bounds__(256) void prep_small(const float* __restrict__ w1,
                                                  const float* __restrict__ w2,
                                                  uint32_t* __restrict__ xpadw,
                                                  uint32_t* __restrict__ hpadw,
                                                  ushort_t* __restrict__ w1t,
                                                  float* __restrict__ w2t){
  int tid = blockIdx.x*256 + threadIdx.x;
  const int NZX = B_*388*64;
  const int NZH = B_*388*128;
  const int NW1 = 256*1152;
  if (tid < NZX){
    zb(xpadw, 64, tid);
  } else if (tid < NZX + NZH){
    zb(hpadw, 128, tid - NZX);
  } else if (tid < NZX + NZH + NW1){
    int r = tid - (NZX + NZH);
    int o = r / 1152, k = r - o*1152;
    int tap = k >> 7, c = k & 127;
    w1t[r] = f2bf(w1[(o*CIN + c)*9 + tap]);
  } else {
    int r = tid - (NZX + NZH + NW1);   // < 4608
    int ch = r & 1, c = (r >> 1) & 255, tap = r >> 9;
    w2t[r] = w2[(ch*CH + c)*9 + tap];
  }
}

// NCHW fp32 -> padded NHWC bf16. Block = (b, y, 32x): stage all 128 c through
// LDS, write FULL 256B lines per pixel (one pixel's whole channel row).
__global__ __launch_bounds__(256) void transform_x(const float* __restrict__ x,
                                                   ushort_t* __restrict__ xpad){
  __shared__ float lds[128][33];
  int bid = blockIdx.x;              // 4608 = 16 b * 96 y * 3 xt
  int xt = bid % 3; int y = (bid/3) % 96; int b = bid/288;
  int x0 = xt*32;
  int t = threadIdx.x;
  #pragma unroll
  for (int rep=0; rep<16; ++rep){
    int idx = rep*256 + t;
    int ci = idx >> 5, xj = idx & 31;
    lds[ci][xj] = x[((b*CIN + ci)*HW + y)*HW + x0 + xj];
  }
  __syncthreads();
  int px = t & 31, oc = t >> 5;      // oc = 16-channel group (0..7)
  ushort_t* dst = &xpad[((b*HP + y+1)*HP + x0+px+1)*CIN + oc*16];
  ushortx8 v0, v1;
  #pragma unroll
  for (int k=0;k<8;k++) v0[k] = f2bf(lds[oc*16+k][px]);
  #pragma unroll
  for (int k=0;k<8;k++) v1[k] = f2bf(lds[oc*16+8+k][px]);
  *(ushortx8*)dst = v0;
  *(ushortx8*)(dst+8) = v1;
}

// ---------------------------------------------------------------------------
// conv1 v5: identical geometry/buffers/ledger/schedule to v4 (BM=256, BN=192,
// BK=64, 18 K-tiles, A 2-buf / B 3-buf, T2 both-sides swizzle, vmcnt(3) per
// K-tile never draining until peeled kt=17, 4-phase interleave, T5 setprio).
// ONLY change: wave tiling 2Mx4N (128x48) -> 4Mx2N (64x96) to balance the
// fragment-read redundancy: per-CU frag traffic 176KB -> 160KB per K-tile.
// acc[4][6]; A-frags read once per k-half and reused across both B phases.
// Per-output-element accumulation order unchanged -> bit-identical output.
// ---------------------------------------------------------------------------
#define C1_TILE(KT, VMN, SA, SB) { \
  asm volatile("s_waitcnt vmcnt(" #VMN ")" ::: "memory"); \
  __builtin_amdgcn_s_barrier(); \
  __builtin_amdgcn_sched_barrier(0); \
  const int kt_ = (KT); \
  const ushort_t* Ab = &Alds[(kt_ & 1) * 16384]; \
  const ushort_t* Bb = &Blds[(kt_ % 3) * 12288]; \
  short8 aa0[4], cc0[4], bb0[3], bb1[3], dd0[3], dd1[3]; \
  /* ---- P0: A[0..3]@k0 + B[0..2]@k0 ; stage A(kt+1) j0,j1 ---- */ \
  _Pragma("unroll") \
  for (int nf=0; nf<3; ++nf) bb0[nf] = *(const short8*)&Bb[bbase_r + nf*1024 + koff0]; \
  _Pragma("unroll") \
  for (int mf=0; mf<4; ++mf) aa0[mf] = *(const short8*)&Ab[abase_r + mf*1024 + koff0]; \
  if (SA) { \
    const int ka_ = kt_ + 1; const int ab_ = (ka_ & 1) * 16384; \
    async_ld16(&Alds[ab_ +     0 + adst], &w1t[asrc +       0 + ka_*64]); \
    async_ld16(&Alds[ab_ +  4096 + adst], &w1t[asrc +   73728 + ka_*64]); \
  } \
  __builtin_amdgcn_s_barrier(); \
  asm volatile("s_waitcnt lgkmcnt(0)" ::: "memory"); \
  __builtin_amdgcn_sched_barrier(0); \
  __builtin_amdgcn_s_setprio(1); \
  _Pragma("unroll") \
  for (int mf=0; mf<4; ++mf) \
    _Pragma("unroll") \
    for (int nf=0; nf<3; ++nf) \
      acc[mf][nf] = __builtin_amdgcn_mfma_f32_16x16x32_bf16(aa0[mf], bb0[nf], acc[mf][nf], 0,0,0); \
  __builtin_amdgcn_s_setprio(0); \
  __builtin_amdgcn_s_barrier(); \
  /* ---- P1: B[3..5]@k0 ; stage A(kt+1) j2,j3 ---- */ \
  _Pragma("unroll") \
  for (int nf=0; nf<3; ++nf) bb1[nf] = *(const short8*)&Bb[bbase_r + (nf+3)*1024 + koff0]; \
  if (SA) { \
    const int ka_ = kt_ + 1; const int ab_ = (ka_ & 1) * 16384; \
    async_ld16(&Alds[ab_ +  8192 + adst], &w1t[asrc + 2*73728 + ka_*64]); \
    async_ld16(&Alds[ab_ + 12288 + adst], &w1t[asrc + 3*73728 + ka_*64]); \
  } \
  __builtin_amdgcn_s_barrier(); \
  asm volatile("s_waitcnt lgkmcnt(0)" ::: "memory"); \
  __builtin_amdgcn_sched_barrier(0); \
  __builtin_amdgcn_s_setprio(1); \
  _Pragma("unroll") \
  for (int mf=0; mf<4; ++mf) \
    _Pragma("unroll") \
    for (int nf=0; nf<3; ++nf) \
      acc[mf][nf+3] = __builtin_amdgcn_mfma_f32_16x16x32_bf16(aa0[mf], bb1[nf], acc[mf][nf+3], 0,0,0); \
  __builtin_amdgcn_s_setprio(0); \
  __builtin_amdgcn_s_barrier(); \
  /* ---- P2: A[0..3]@k1 + B[0..2]@k1 ; stage B(kt+2) j0,j1 ---- */ \
  _Pragma("unroll") \
  for (int nf=0; nf<3; ++nf) dd0[nf] = *(const short8*)&Bb[bbase_r + nf*1024 + koff1]; \
  _Pragma("unroll") \
  for (int mf=0; mf<4; ++mf) cc0[mf] = *(const short8*)&Ab[abase_r + mf*1024 + koff1]; \
  if (SB) { \
    const int kb_ = kt_ + 2; \
    const int tapb_ = kb_ >> 1; \
    const int dyb_ = tapb_/3; const int dxb_ = tapb_ - dyb_*3; \
    const int bdb_ = (dyb_*HP + dxb_)*CIN + (kb_&1)*64; \
    const int bb_ = (kb_ % 3) * 12288; \
    async_ld16(&Blds[bb_ +    0 + bdst], &xpad[bsrc +            bdb_]); \
    async_ld16(&Blds[bb_ + 4096 + bdst], &xpad[bsrc + 2*HP*CIN + bdb_]); \
  } \
  __builtin_amdgcn_s_barrier(); \
  asm volatile("s_waitcnt lgkmcnt(0)" ::: "memory"); \
  __builtin_amdgcn_sched_barrier(0); \
  __builtin_amdgcn_s_setprio(1); \
  _Pragma("unroll") \
  for (int mf=0; mf<4; ++mf) \
    _Pragma("unroll") \
    for (int nf=0; nf<3; ++nf) \
      acc[mf][nf] = __builtin_amdgcn_mfma_f32_16x16x32_bf16(cc0[mf], dd0[nf], acc[mf][nf], 0,0,0); \
  __builtin_amdgcn_s_setprio(0); \
  __builtin_amdgcn_s_barrier(); \
  /* ---- P3: B[3..5]@k1 ; stage B(kt+2) j2 ---- */ \
  _Pragma("unroll") \
  for (int nf=0; nf<3; ++nf) dd1[nf] = *(const short8*)&Bb[bbase_r + (nf+3)*1024 + koff1]; \
  if (SB) { \
    const int kb_ = kt_ + 2; \
    const int tapb_ = kb_ >> 1; \
    const int dyb_ = tapb_/3; const int dxb_ = tapb_ - dyb_*3; \
    const int bdb_ = (dyb_*HP + dxb_)*CIN + (kb_&1)*64; \
    const int bb_ = (kb_ % 3) * 12288; \
    async_ld16(&Blds[bb_ + 8192 + bdst], &xpad[bsrc + 4*HP*CIN + bdb_]); \
  } \
  __builtin_amdgcn_s_barrier(); \
  asm volatile("s_waitcnt lgkmcnt(0)" ::: "memory"); \
  __builtin_amdgcn_sched_barrier(0); \
  __builtin_amdgcn_s_setprio(1); \
  _Pragma("unroll") \
  for (int mf=0; mf<4; ++mf) \
    _Pragma("unroll") \
    for (int nf=0; nf<3; ++nf) \
      acc[mf][nf+3] = __builtin_amdgcn_mfma_f32_16x16x32_bf16(cc0[mf], dd1[nf], acc[mf][nf+3], 0,0,0); \
  __builtin_amdgcn_s_setprio(0); \
}

__global__ __launch_bounds__(512, 1) void conv1(const ushort_t* __restrict__ xpad,
                                                const ushort_t* __restrict__ w1t,
                                                const float* __restrict__ b1,
                                                ushort_t* __restrict__ hpad){
  __shared__ __align__(16) ushort_t Alds[2*16384];   // 2 bufs x 256 rows x 64 (64 KB)
  __shared__ __align__(16) ushort_t Blds[3*12288];   // 3 bufs x 192 rows x 64 (72 KB)
  int orig = blockIdx.x;
  int bid = (orig & 7) * 96 + (orig >> 3);           // XCD swizzle, 768 % 8 == 0
  int b = bid / 48; int rem = bid - b*48;
  int y0 = (rem/3)*6, x0 = (rem - (rem/3)*3)*32;     // 6y x 32x pixel tile
  int t = threadIdx.x;
  int lane = t & 63, wave = t >> 6;
  int wm = wave & 3, wn = wave >> 2;                 // 4M x 2N waves (wave tile 64x96)
  int r = lane & 15, q = lane >> 4;

  // staging maps (granule v = j*512 + t; row = v>>3; stored oct = v&7 holds
  // logical oct (v&7)^(row&7) -> source pre-swizzled, LDS dest linear)
  const int arow0 = t >> 3;                          // 0..63 (j adds 64 each)
  const int soct  = (t & 7) ^ (arow0 & 7);           // same for all j (64%8==0)
  const int adst  = t * 8;                           // + j*4096 + buf*16384
  const int asrc  = arow0 * 1152 + soct * 8;         // + j*73728 + kt*64
  const int bty0  = arow0 >> 5, btx0 = arow0 & 31;   // B row = pixel index
  const int bdst  = t * 8;                           // + j*4096 + buf*12288
  const int bsrc  = ((b*HP + y0 + bty0)*HP + x0 + btx0)*CIN + soct * 8; // + j*2*HP*CIN + bd

  // fragment read offsets (ushort units); row&7 == r&7 for all frag rows
  const int koff0 = ((0*4 + q) ^ (r & 7)) * 8;
  const int koff1 = ((1*4 + q) ^ (r & 7)) * 8;
  const int abase_r = (wm*64 + r) * 64;              // + mf*1024 (mf 0..3)
  const int bbase_r = (wn*96 + r) * 64;              // + nf*1024 (nf 0..5)

  floatx4 acc[4][6];
  #pragma unroll
  for (int i=0;i<4;i++)
    #pragma unroll
    for (int j=0;j<6;j++) acc[i][j] = (floatx4){0.f,0.f,0.f,0.f};

  // prologue: ledger order B-for-0(3), A-for-0(4), B-for-1(3)
  #pragma unroll
  for (int j=0;j<3;++j) async_ld16(&Blds[0     + j*4096 + bdst], &xpad[bsrc + j*(2*HP*CIN)]);
  #pragma unroll
  for (int j=0;j<4;++j) async_ld16(&Alds[0     + j*4096 + adst], &w1t[asrc + j*73728]);
  #pragma unroll
  for (int j=0;j<3;++j) async_ld16(&Blds[12288 + j*4096 + bdst], &xpad[bsrc + j*(2*HP*CIN) + 64]);

  for (int kt=0; kt<16; ++kt){
    C1_TILE(kt, 3, 1, 1)
  }
  C1_TILE(16, 3, 1, 0)
  C1_TILE(17, 0, 0, 0)

  // epilogue: +bias, ReLU, bf16, store padded NHWC h
  #pragma unroll
  for (int mf=0; mf<4; ++mf){
    int o = wm*64 + mf*16 + q*4;
    float bias0 = b1[o], bias1 = b1[o+1], bias2 = b1[o+2], bias3 = b1[o+3];
    #pragma unroll
    for (int nf=0; nf<6; ++nf){
      int n = wn*96 + nf*16 + r;
      int ty = n >> 5, tx = n & 31;
      ushortx4 v;
      v[0] = f2bf(fmaxf(acc[mf][nf][0] + bias0, 0.f));
      v[1] = f2bf(fmaxf(acc[mf][nf][1] + bias1, 0.f));
      v[2] = f2bf(fmaxf(acc[mf][nf][2] + bias2, 0.f));
      v[3] = f2bf(fmaxf(acc[mf][nf][3] + bias3, 0.f));
      *(ushortx4*)&hpad[((b*HP + y0+ty+1)*HP + (x0+tx+1))*CH + o] = v;
    }
  }
}

// conv2: LDS-staged direct 3x3. Block = 8x8 output tile, halo 10x10 cells x 512B
// staged into LDS (51.2 KB) via global_load_lds: LDS dest linear, global SOURCE
// pre-swizzled chunk ^ (cell&7); reads apply the same XOR (both-sides involution).
// Wave = channel quarter (w addresses wave-uniform -> scalar cache); lane = pixel.
__global__ __launch_bounds__(256) void conv2(const ushort_t* __restrict__ hpad,
                                             const float* __restrict__ w2t,
                                             const float* __restrict__ b2,
                                             float* __restrict__ out){
  __shared__ __align__(16) ushort_t hlds[25600];   // 100 cells * 256 ushorts
  __shared__ float part[4][64][2];
  int bid = blockIdx.x;              // 2304 = 16 b * 12 yt * 12 xt
  int b = bid / 144; int rem = bid - b*144;
  int yt = rem / 12, xt = rem - yt*12;
  int y0 = yt*8, x0 = xt*8;          // padded window base = (y0, x0)
  int t = threadIdx.x;
  int wave = t >> 6, lane = t & 63;

  // stage 3200 x 16B chunks, pre-swizzled source
  for (int pass=0; pass<13; ++pass){
    int u = pass*256 + t;
    if (u < 3200){
      int cell = u >> 5, cf = u & 31;
      int hy = cell / 10, hx = cell - hy*10;
      const ushort_t* src = hpad + ((b*HP + y0+hy)*HP + (x0+hx))*CH
                                 + ((cf ^ (cell & 7)) << 3);
      async_ld16(&hlds[(pass*256 + wave*64)*8], src);
    }
  }
  __syncthreads();

  int q = __builtin_amdgcn_readfirstlane(wave);    // channel quarter, provably uniform
  int ty = lane >> 3, tx = lane & 7;
  float a0 = 0.f, a1 = 0.f;
  for (int tap=0; tap<9; ++tap){
    int dy = tap/3, dxx = tap - dy*3;
    int cell = (ty+dy)*10 + (tx+dxx);
    int s = cell & 7;
    const float* wp = w2t + (tap*256 + q*64)*2;    // scalar pointer
    #pragma unroll
    for (int g=0; g<8; ++g){
      int j = q*8 + g;
      ushortx8 hv = *(const ushortx8*)&hlds[cell*256 + ((j ^ s) << 3)];
      #pragma unroll
      for (int i=0;i<8;i++){
        float hf = bf2f(hv[i]);
        a0 = fmaf(hf, wp[(g*8+i)*2    ], a0);
        a1 = fmaf(hf, wp[(g*8+i)*2 + 1], a1);
      }
    }
  }
  part[wave][lane][0] = a0;
  part[wave][lane][1] = a1;
  __syncthreads();
  if (t < 128){
    int sel = t >> 6, pix = t & 63;
    float v = part[0][pix][sel] + part[1][pix][sel]
            + part[2][pix][sel] + part[3][pix][sel] + b2[sel];
    int yy = y0 + (pix >> 3), xx = x0 + (pix & 7);
    out[(b*2 + sel)*9216 + yy*96 + xx] = v;
  }
}

extern "C" void kernel_launch(void* const* d_in, const int* in_sizes, int n_in,
                              void* d_out, int out_size, void* d_ws, size_t ws_size,
                              hipStream_t stream){
  const float* x  = (const float*)d_in[0];
  const float* w1 = (const float*)d_in[1];
  const float* b1 = (const float*)d_in[2];
  const float* w2 = (const float*)d_in[3];
  const float* b2 = (const float*)d_in[4];
  float* out = (float*)d_out;
  char* ws = (char*)d_ws;
  ushort_t* xpad = (ushort_t*)(ws + XPAD_OFF);
  ushort_t* hpad = (ushort_t*)(ws + HPAD_OFF);
  ushort_t* w1t  = (ushort_t*)(ws + W1T_OFF);
  float*    w2t  = (float*)(ws + W2T_OFF);

  hipLaunchKernelGGL(prep_small,  dim3(5826), dim3(256), 0, stream,
                     w1, w2, (uint32_t*)xpad, (uint32_t*)hpad, w1t, w2t);
  hipLaunchKernelGGL(transform_x, dim3(4608), dim3(256), 0, stream, x, xpad);
  hipLaunchKernelGGL(conv1, dim3(768),  dim3(512), 0, stream, xpad, w1t, b1, hpad);
  hipLaunchKernelGGL(conv2, dim3(2304), dim3(256), 0, stream, hpad, w2t, b2, out);
}

// Round 9
// 157.880 us; speedup vs baseline: 1.4928x; 1.0160x over previous
//
#include <hip/hip_runtime.h>
#include <stdint.h>

typedef unsigned short ushort_t;
typedef __attribute__((ext_vector_type(8))) short short8;
typedef __attribute__((ext_vector_type(4))) float floatx4;
typedef __attribute__((ext_vector_type(4))) unsigned short ushortx4;
typedef __attribute__((ext_vector_type(8))) unsigned short ushortx8;

#define B_   16
#define CIN  128
#define CH   256
#define HW   96
#define HP   98

// ws layout (bytes)
#define XPAD_ELEMS (B_*HP*HP*CIN)            // bf16 elems
#define HPAD_ELEMS (B_*HP*HP*CH)             // bf16 elems
#define XPAD_OFF 0
#define HPAD_OFF (XPAD_ELEMS*2)
#define W1T_OFF  (HPAD_OFF + HPAD_ELEMS*2)
#define W2T_OFF  (W1T_OFF + 256*1152*2)

__device__ __forceinline__ ushort_t f2bf(float f){
  uint32_t u = __float_as_uint(f);
  u += 0x7FFF + ((u >> 16) & 1);   // RNE
  return (ushort_t)(u >> 16);
}
__device__ __forceinline__ float bf2f(ushort_t h){
  return __uint_as_float(((uint32_t)h) << 16);
}
__device__ __forceinline__ void async_ld16(void* lds, const void* g){
  __builtin_amdgcn_global_load_lds(
      (const __attribute__((address_space(1))) void*)g,
      (__attribute__((address_space(3))) void*)lds, 16, 0, 0);
}

// Zero one border word of a padded NHWC tensor. C2 = channels/2 (u32 words/cell).
__device__ __forceinline__ void zb(uint32_t* base, int C2, int tid){
  int perimg = 388*C2;
  int b = tid / perimg; int r = tid % perimg;
  int cell = r / C2;    int cu = r % C2;
  int y, x;
  if      (cell < 98)  { y = 0;            x = cell;       }
  else if (cell < 196) { y = 97;           x = cell - 98;  }
  else if (cell < 292) { y = cell - 195;   x = 0;          }
  else                 { y = cell - 291;   x = 97;         }
  base[((b*HP + y)*HP + x)*C2 + cu] = 0u;
}

// Fused prep: blocks [0,4608) = transform_x (NCHW fp32 -> padded NHWC bf16,
// full 256B-line stores); blocks [4608,10434) = border zeroing + w transforms.
__global__ __launch_bounds__(256) void prep_all(const float* __restrict__ x,
                                                const float* __restrict__ w1,
                                                const float* __restrict__ w2,
                                                uint32_t* __restrict__ xpadw,
                                                uint32_t* __restrict__ hpadw,
                                                ushort_t* __restrict__ w1t,
                                                float* __restrict__ w2t,
                                                ushort_t* __restrict__ xpad){
  __shared__ float lds[128][33];
  int bidx = blockIdx.x;
  int t = threadIdx.x;
  if (bidx < 4608){
    int xt = bidx % 3; int y = (bidx/3) % 96; int b = bidx/288;
    int x0 = xt*32;
    #pragma unroll
    for (int rep=0; rep<16; ++rep){
      int idx = rep*256 + t;
      int ci = idx >> 5, xj = idx & 31;
      lds[ci][xj] = x[((b*CIN + ci)*HW + y)*HW + x0 + xj];
    }
    __syncthreads();
    int px = t & 31, oc = t >> 5;      // oc = 16-channel group (0..7)
    ushort_t* dst = &xpad[((b*HP + y+1)*HP + x0+px+1)*CIN + oc*16];
    ushortx8 v0, v1;
    #pragma unroll
    for (int k=0;k<8;k++) v0[k] = f2bf(lds[oc*16+k][px]);
    #pragma unroll
    for (int k=0;k<8;k++) v1[k] = f2bf(lds[oc*16+8+k][px]);
    *(ushortx8*)dst = v0;
    *(ushortx8*)(dst+8) = v1;
  } else {
    int tid = (bidx - 4608)*256 + t;
    const int NZX = B_*388*64;
    const int NZH = B_*388*128;
    const int NW1 = 256*1152;
    if (tid < NZX){
      zb(xpadw, 64, tid);
    } else if (tid < NZX + NZH){
      zb(hpadw, 128, tid - NZX);
    } else if (tid < NZX + NZH + NW1){
      int r = tid - (NZX + NZH);
      int o = r / 1152, k = r - o*1152;
      int tap = k >> 7, c = k & 127;
      w1t[r] = f2bf(w1[(o*CIN + c)*9 + tap]);
    } else {
      int r = tid - (NZX + NZH + NW1);   // < 4608
      int ch = r & 1, c = (r >> 1) & 255, tap = r >> 9;
      w2t[r] = w2[(ch*CH + c)*9 + tap];
    }
  }
}

// ---------------------------------------------------------------------------
// conv1 v6: geometry/buffers/ledger identical to v5 (BM=256, BN=192, BK=64,
// 18 K-tiles, 4Mx2N waves 64x96, A 2-buf / B 3-buf, T2 both-sides swizzle,
// vmcnt(3) per K-tile, 4-phase barriers, T5 setprio).
// NEW: fragment ds_reads are issued ONE PHASE AHEAD (register prefetch) and
// the forced lgkmcnt(0) drains are removed — the compiler emits minimal
// counted lgkmcnt before each MFMA cluster's first operand use, leaving the
// prefetched reads in flight under the MFMAs. Only the tile-entry read group
// (R0) stays latency-exposed (was 4 exposures, now 1).
// Per-output-element accumulation order unchanged -> bit-identical output.
// ---------------------------------------------------------------------------
#define C1_TILE(KT, VMN, SA, SB) { \
  asm volatile("s_waitcnt vmcnt(" #VMN ")" ::: "memory"); \
  __builtin_amdgcn_s_barrier(); \
  __builtin_amdgcn_sched_barrier(0); \
  const int kt_ = (KT); \
  const ushort_t* Ab = &Alds[(kt_ & 1) * 16384]; \
  const ushort_t* Bb = &Blds[(kt_ % 3) * 12288]; \
  short8 a0[4], a1[4], b0[3], b1[3], b2[3], b3[3]; \
  /* R0: frags for P0 (exposed at tile entry) */ \
  _Pragma("unroll") \
  for (int nf=0; nf<3; ++nf) b0[nf] = *(const short8*)&Bb[bbase_r + nf*1024 + koff0]; \
  _Pragma("unroll") \
  for (int mf=0; mf<4; ++mf) a0[mf] = *(const short8*)&Ab[abase_r + mf*1024 + koff0]; \
  /* ---- P0: issue R1 (P1 frags); stage A(kt+1) j0,j1; MFMA a0*b0 ---- */ \
  _Pragma("unroll") \
  for (int nf=0; nf<3; ++nf) b1[nf] = *(const short8*)&Bb[bbase_r + (nf+3)*1024 + koff0]; \
  if (SA) { \
    const int ka_ = kt_ + 1; const int ab_ = (ka_ & 1) * 16384; \
    async_ld16(&Alds[ab_ +     0 + adst], &w1t[asrc +       0 + ka_*64]); \
    async_ld16(&Alds[ab_ +  4096 + adst], &w1t[asrc +   73728 + ka_*64]); \
  } \
  __builtin_amdgcn_s_barrier(); \
  __builtin_amdgcn_sched_barrier(0); \
  __builtin_amdgcn_s_setprio(1); \
  _Pragma("unroll") \
  for (int mf=0; mf<4; ++mf) \
    _Pragma("unroll") \
    for (int nf=0; nf<3; ++nf) \
      acc[mf][nf] = __builtin_amdgcn_mfma_f32_16x16x32_bf16(a0[mf], b0[nf], acc[mf][nf], 0,0,0); \
  __builtin_amdgcn_s_setprio(0); \
  __builtin_amdgcn_s_barrier(); \
  __builtin_amdgcn_sched_barrier(0); \
  /* ---- P1: issue R2 (P2 frags); stage A(kt+1) j2,j3; MFMA a0*b1 ---- */ \
  _Pragma("unroll") \
  for (int mf=0; mf<4; ++mf) a1[mf] = *(const short8*)&Ab[abase_r + mf*1024 + koff1]; \
  _Pragma("unroll") \
  for (int nf=0; nf<3; ++nf) b2[nf] = *(const short8*)&Bb[bbase_r + nf*1024 + koff1]; \
  if (SA) { \
    const int ka_ = kt_ + 1; const int ab_ = (ka_ & 1) * 16384; \
    async_ld16(&Alds[ab_ +  8192 + adst], &w1t[asrc + 2*73728 + ka_*64]); \
    async_ld16(&Alds[ab_ + 12288 + adst], &w1t[asrc + 3*73728 + ka_*64]); \
  } \
  __builtin_amdgcn_s_barrier(); \
  __builtin_amdgcn_sched_barrier(0); \
  __builtin_amdgcn_s_setprio(1); \
  _Pragma("unroll") \
  for (int mf=0; mf<4; ++mf) \
    _Pragma("unroll") \
    for (int nf=0; nf<3; ++nf) \
      acc[mf][nf+3] = __builtin_amdgcn_mfma_f32_16x16x32_bf16(a0[mf], b1[nf], acc[mf][nf+3], 0,0,0); \
  __builtin_amdgcn_s_setprio(0); \
  __builtin_amdgcn_s_barrier(); \
  __builtin_amdgcn_sched_barrier(0); \
  /* ---- P2: issue R3 (P3 frags); stage B(kt+2) j0,j1; MFMA a1*b2 ---- */ \
  _Pragma("unroll") \
  for (int nf=0; nf<3; ++nf) b3[nf] = *(const short8*)&Bb[bbase_r + (nf+3)*1024 + koff1]; \
  if (SB) { \
    const int kb_ = kt_ + 2; \
    const int tapb_ = kb_ >> 1; \
    const int dyb_ = tapb_/3; const int dxb_ = tapb_ - dyb_*3; \
    const int bdb_ = (dyb_*HP + dxb_)*CIN + (kb_&1)*64; \
    const int bb_ = (kb_ % 3) * 12288; \
    async_ld16(&Blds[bb_ +    0 + bdst], &xpad[bsrc +            bdb_]); \
    async_ld16(&Blds[bb_ + 4096 + bdst], &xpad[bsrc + 2*HP*CIN + bdb_]); \
  } \
  __builtin_amdgcn_s_barrier(); \
  __builtin_amdgcn_sched_barrier(0); \
  __builtin_amdgcn_s_setprio(1); \
  _Pragma("unroll") \
  for (int mf=0; mf<4; ++mf) \
    _Pragma("unroll") \
    for (int nf=0; nf<3; ++nf) \
      acc[mf][nf] = __builtin_amdgcn_mfma_f32_16x16x32_bf16(a1[mf], b2[nf], acc[mf][nf], 0,0,0); \
  __builtin_amdgcn_s_setprio(0); \
  __builtin_amdgcn_s_barrier(); \
  __builtin_amdgcn_sched_barrier(0); \
  /* ---- P3: stage B(kt+2) j2; MFMA a1*b3 ---- */ \
  if (SB) { \
    const int kb_ = kt_ + 2; \
    const int tapb_ = kb_ >> 1; \
    const int dyb_ = tapb_/3; const int dxb_ = tapb_ - dyb_*3; \
    const int bdb_ = (dyb_*HP + dxb_)*CIN + (kb_&1)*64; \
    const int bb_ = (kb_ % 3) * 12288; \
    async_ld16(&Blds[bb_ + 8192 + bdst], &xpad[bsrc + 4*HP*CIN + bdb_]); \
  } \
  __builtin_amdgcn_s_barrier(); \
  __builtin_amdgcn_sched_barrier(0); \
  __builtin_amdgcn_s_setprio(1); \
  _Pragma("unroll") \
  for (int mf=0; mf<4; ++mf) \
    _Pragma("unroll") \
    for (int nf=0; nf<3; ++nf) \
      acc[mf][nf+3] = __builtin_amdgcn_mfma_f32_16x16x32_bf16(a1[mf], b3[nf], acc[mf][nf+3], 0,0,0); \
  __builtin_amdgcn_s_setprio(0); \
}

__global__ __launch_bounds__(512, 1) void conv1(const ushort_t* __restrict__ xpad,
                                                const ushort_t* __restrict__ w1t,
                                                const float* __restrict__ b1,
                                                ushort_t* __restrict__ hpad){
  __shared__ __align__(16) ushort_t Alds[2*16384];   // 2 bufs x 256 rows x 64 (64 KB)
  __shared__ __align__(16) ushort_t Blds[3*12288];   // 3 bufs x 192 rows x 64 (72 KB)
  int orig = blockIdx.x;
  int bid = (orig & 7) * 96 + (orig >> 3);           // XCD swizzle, 768 % 8 == 0
  int b = bid / 48; int rem = bid - b*48;
  int y0 = (rem/3)*6, x0 = (rem - (rem/3)*3)*32;     // 6y x 32x pixel tile
  int t = threadIdx.x;
  int lane = t & 63, wave = t >> 6;
  int wm = wave & 3, wn = wave >> 2;                 // 4M x 2N waves (wave tile 64x96)
  int r = lane & 15, q = lane >> 4;

  // staging maps (granule v = j*512 + t; row = v>>3; stored oct = v&7 holds
  // logical oct (v&7)^(row&7) -> source pre-swizzled, LDS dest linear)
  const int arow0 = t >> 3;                          // 0..63 (j adds 64 each)
  const int soct  = (t & 7) ^ (arow0 & 7);           // same for all j (64%8==0)
  const int adst  = t * 8;                           // + j*4096 + buf*16384
  const int asrc  = arow0 * 1152 + soct * 8;         // + j*73728 + kt*64
  const int bty0  = arow0 >> 5, btx0 = arow0 & 31;   // B row = pixel index
  const int bdst  = t * 8;                           // + j*4096 + buf*12288
  const int bsrc  = ((b*HP + y0 + bty0)*HP + x0 + btx0)*CIN + soct * 8; // + j*2*HP*CIN + bd

  // fragment read offsets (ushort units); row&7 == r&7 for all frag rows
  const int koff0 = ((0*4 + q) ^ (r & 7)) * 8;
  const int koff1 = ((1*4 + q) ^ (r & 7)) * 8;
  const int abase_r = (wm*64 + r) * 64;              // + mf*1024 (mf 0..3)
  const int bbase_r = (wn*96 + r) * 64;              // + nf*1024 (nf 0..5)

  floatx4 acc[4][6];
  #pragma unroll
  for (int i=0;i<4;i++)
    #pragma unroll
    for (int j=0;j<6;j++) acc[i][j] = (floatx4){0.f,0.f,0.f,0.f};

  // prologue: ledger order B-for-0(3), A-for-0(4), B-for-1(3)
  #pragma unroll
  for (int j=0;j<3;++j) async_ld16(&Blds[0     + j*4096 + bdst], &xpad[bsrc + j*(2*HP*CIN)]);
  #pragma unroll
  for (int j=0;j<4;++j) async_ld16(&Alds[0     + j*4096 + adst], &w1t[asrc + j*73728]);
  #pragma unroll
  for (int j=0;j<3;++j) async_ld16(&Blds[12288 + j*4096 + bdst], &xpad[bsrc + j*(2*HP*CIN) + 64]);

  for (int kt=0; kt<16; ++kt){
    C1_TILE(kt, 3, 1, 1)
  }
  C1_TILE(16, 3, 1, 0)
  C1_TILE(17, 0, 0, 0)

  // epilogue: +bias, ReLU, bf16, store padded NHWC h
  #pragma unroll
  for (int mf=0; mf<4; ++mf){
    int o = wm*64 + mf*16 + q*4;
    float bias0 = b1[o], bias1 = b1[o+1], bias2 = b1[o+2], bias3 = b1[o+3];
    #pragma unroll
    for (int nf=0; nf<6; ++nf){
      int n = wn*96 + nf*16 + r;
      int ty = n >> 5, tx = n & 31;
      ushortx4 v;
      v[0] = f2bf(fmaxf(acc[mf][nf][0] + bias0, 0.f));
      v[1] = f2bf(fmaxf(acc[mf][nf][1] + bias1, 0.f));
      v[2] = f2bf(fmaxf(acc[mf][nf][2] + bias2, 0.f));
      v[3] = f2bf(fmaxf(acc[mf][nf][3] + bias3, 0.f));
      *(ushortx4*)&hpad[((b*HP + y0+ty+1)*HP + (x0+tx+1))*CH + o] = v;
    }
  }
}

// conv2: LDS-staged direct 3x3. Block = 8x8 output tile, halo 10x10 cells x 512B
// staged into LDS (51.2 KB) via global_load_lds: LDS dest linear, global SOURCE
// pre-swizzled chunk ^ (cell&7); reads apply the same XOR (both-sides involution).
// Wave = channel quarter (w addresses wave-uniform -> scalar cache); lane = pixel.
__global__ __launch_bounds__(256) void conv2(const ushort_t* __restrict__ hpad,
                                             const float* __restrict__ w2t,
                                             const float* __restrict__ b2,
                                             float* __restrict__ out){
  __shared__ __align__(16) ushort_t hlds[25600];   // 100 cells * 256 ushorts
  __shared__ float part[4][64][2];
  int bid = blockIdx.x;              // 2304 = 16 b * 12 yt * 12 xt
  int b = bid / 144; int rem = bid - b*144;
  int yt = rem / 12, xt = rem - yt*12;
  int y0 = yt*8, x0 = xt*8;          // padded window base = (y0, x0)
  int t = threadIdx.x;
  int wave = t >> 6, lane = t & 63;

  // stage 3200 x 16B chunks, pre-swizzled source
  for (int pass=0; pass<13; ++pass){
    int u = pass*256 + t;
    if (u < 3200){
      int cell = u >> 5, cf = u & 31;
      int hy = cell / 10, hx = cell - hy*10;
      const ushort_t* src = hpad + ((b*HP + y0+hy)*HP + (x0+hx))*CH
                                 + ((cf ^ (cell & 7)) << 3);
      async_ld16(&hlds[(pass*256 + wave*64)*8], src);
    }
  }
  __syncthreads();

  int q = __builtin_amdgcn_readfirstlane(wave);    // channel quarter, provably uniform
  int ty = lane >> 3, tx = lane & 7;
  float a0 = 0.f, a1 = 0.f;
  for (int tap=0; tap<9; ++tap){
    int dy = tap/3, dxx = tap - dy*3;
    int cell = (ty+dy)*10 + (tx+dxx);
    int s = cell & 7;
    const float* wp = w2t + (tap*256 + q*64)*2;    // scalar pointer
    #pragma unroll
    for (int g=0; g<8; ++g){
      int j = q*8 + g;
      ushortx8 hv = *(const ushortx8*)&hlds[cell*256 + ((j ^ s) << 3)];
      #pragma unroll
      for (int i=0;i<8;i++){
        float hf = bf2f(hv[i]);
        a0 = fmaf(hf, wp[(g*8+i)*2    ], a0);
        a1 = fmaf(hf, wp[(g*8+i)*2 + 1], a1);
      }
    }
  }
  part[wave][lane][0] = a0;
  part[wave][lane][1] = a1;
  __syncthreads();
  if (t < 128){
    int sel = t >> 6, pix = t & 63;
    float v = part[0][pix][sel] + part[1][pix][sel]
            + part[2][pix][sel] + part[3][pix][sel] + b2[sel];
    int yy = y0 + (pix >> 3), xx = x0 + (pix & 7);
    out[(b*2 + sel)*9216 + yy*96 + xx] = v;
  }
}

extern "C" void kernel_launch(void* const* d_in, const int* in_sizes, int n_in,
                              void* d_out, int out_size, void* d_ws, size_t ws_size,
                              hipStream_t stream){
  const float* x  = (const float*)d_in[0];
  const float* w1 = (const float*)d_in[1];
  const float* b1 = (const float*)d_in[2];
  const float* w2 = (const float*)d_in[3];
  const float* b2 = (const float*)d_in[4];
  float* out = (float*)d_out;
  char* ws = (char*)d_ws;
  ushort_t* xpad = (ushort_t*)(ws + XPAD_OFF);
  ushort_t* hpad = (ushort_t*)(ws + HPAD_OFF);
  ushort_t* w1t  = (ushort_t*)(ws + W1T_OFF);
  float*    w2t  = (float*)(ws + W2T_OFF);

  hipLaunchKernelGGL(prep_all, dim3(10434), dim3(256), 0, stream,
                     x, w1, w2, (uint32_t*)xpad, (uint32_t*)hpad, w1t, w2t, xpad);
  hipLaunchKernelGGL(conv1, dim3(768),  dim3(512), 0, stream, xpad, w1t, b1, hpad);
  hipLaunchKernelGGL(conv2, dim3(2304), dim3(256), 0, stream, hpad, w2t, b2, out);
}